// Round 9
// baseline (423.478 us; speedup 1.0000x reference)
//
#include <hip/hip_runtime.h>
#include <hip/hip_bf16.h>

// MoE top-2, T=32768 tokens, D=1024, E=8.
// Pipeline: gate(4 tok/wave) -> hist -> scan -> scatter(+inverse map) -> wconv
//           -> grouped GEMM (m201-style 256^2 8-phase, K-split half-tiles, vmcnt(6)) -> combine.

typedef __attribute__((ext_vector_type(8))) short short8_t;
typedef __attribute__((ext_vector_type(4))) float f32x4_t;

#define GLOAD_LDS16(g, l)                                                                     \
  __builtin_amdgcn_global_load_lds((const __attribute__((address_space(1))) unsigned int*)(g), \
                                   (__attribute__((address_space(3))) unsigned int*)(l), 16, 0, 0)

__device__ __forceinline__ unsigned short f2bf(float f) {
  union { __hip_bfloat16 h; unsigned short u; } c;
  c.h = __float2bfloat16(f);
  return c.u;
}

// ---------------- gate: 4 tokens/wave; fp32 logits, top-2 softmax; x -> bf16 ----------------
__global__ __launch_bounds__(256) void gate_kernel(
    const float* __restrict__ x, const float* __restrict__ gw,
    unsigned short* __restrict__ xb,
    int* __restrict__ tok_e, float* __restrict__ tok_w)
{
  int wid = threadIdx.x >> 6, lane = threadIdx.x & 63;
  int t0 = (blockIdx.x << 4) + (wid << 2);              // 4 tokens per wave
  const float4* g4 = (const float4*)gw;                 // gw is [1024][8] row-major
  float lg[4][8] = {};
  #pragma unroll
  for (int c = 0; c < 4; ++c) {
    int d4 = (c << 6) + lane;                           // float4 index within a row
    float4 ga[4], gb[4];
    #pragma unroll
    for (int j = 0; j < 4; ++j) {
      int d = (d4 << 2) + j;
      ga[j] = g4[d << 1];
      gb[j] = g4[(d << 1) + 1];
    }
    #pragma unroll
    for (int t = 0; t < 4; ++t) {                       // reuse gw regs across 4 tokens
      const float4* x4 = (const float4*)(x + ((size_t)(t0 + t) << 10));
      float4 v = x4[d4];
      unsigned long long pk = (unsigned long long)f2bf(v.x)
                            | ((unsigned long long)f2bf(v.y) << 16)
                            | ((unsigned long long)f2bf(v.z) << 32)
                            | ((unsigned long long)f2bf(v.w) << 48);
      ((unsigned long long*)(xb + ((size_t)(t0 + t) << 10)))[d4] = pk;
      float xs[4] = {v.x, v.y, v.z, v.w};
      #pragma unroll
      for (int j = 0; j < 4; ++j) {
        lg[t][0] += xs[j]*ga[j].x; lg[t][1] += xs[j]*ga[j].y;
        lg[t][2] += xs[j]*ga[j].z; lg[t][3] += xs[j]*ga[j].w;
        lg[t][4] += xs[j]*gb[j].x; lg[t][5] += xs[j]*gb[j].y;
        lg[t][6] += xs[j]*gb[j].z; lg[t][7] += xs[j]*gb[j].w;
      }
    }
  }
  #pragma unroll
  for (int t = 0; t < 4; ++t)
    #pragma unroll
    for (int e = 0; e < 8; ++e) {
      float v = lg[t][e];
      #pragma unroll
      for (int s = 32; s > 0; s >>= 1) v += __shfl_xor(v, s, 64);
      lg[t][e] = v;
    }
  if (lane < 4) {                                       // lane t finalizes token t0+t
    int t = t0 + lane;
    float m0 = lg[lane][0], m1 = -3.4e38f; int e0 = 0, e1 = 0;
    #pragma unroll
    for (int e = 1; e < 8; ++e) {                       // strict '>' matches jax top_k ties
      float v = lg[lane][e];
      if (v > m0) { m1 = m0; e1 = e0; m0 = v; e0 = e; }
      else if (v > m1) { m1 = v; e1 = e; }
    }
    float p1 = 1.0f / (1.0f + expf(m0 - m1));
    float p0 = 1.0f - p1;
    int i0 = t << 1;
    tok_e[i0]   = e0; tok_w[i0]   = p0;
    tok_e[i0+1] = e1; tok_w[i0+1] = p1;
  }
}

// ---------------- hist: per-256-entry chunk, LDS histogram + local rank ----------------
__global__ __launch_bounds__(256) void hist_kernel(
    const int* __restrict__ tok_e, int* __restrict__ tok_r, int* __restrict__ chunkhist)
{
  __shared__ int lh[8];
  if (threadIdx.x < 8) lh[threadIdx.x] = 0;
  __syncthreads();
  int i = (blockIdx.x << 8) + threadIdx.x;
  int e = tok_e[i];
  tok_r[i] = atomicAdd(&lh[e], 1);
  __syncthreads();
  if (threadIdx.x < 8) chunkhist[(blockIdx.x << 3) + threadIdx.x] = lh[threadIdx.x];
}

// ---------------- scan: 8 waves, wave e scans expert e across 256 chunks ----------------
__global__ __launch_bounds__(512) void scan_kernel(
    const int* __restrict__ chunkhist, int* __restrict__ base, int* __restrict__ ctrl)
{
  __shared__ int h[2048];
  __shared__ int bx[2048];
  __shared__ int tot[8], eoff[8];
  for (int i = threadIdx.x; i < 2048; i += 512) h[i] = chunkhist[i];
  __syncthreads();
  int wid = threadIdx.x >> 6, lane = threadIdx.x & 63;
  int running = 0;
  #pragma unroll
  for (int b = 0; b < 4; ++b) {
    int c = (b << 6) + lane;
    int orig = h[(c << 3) + wid];
    int v = orig;
    #pragma unroll
    for (int s = 1; s < 64; s <<= 1) {
      int u = __shfl_up(v, s, 64);
      if (lane >= s) v += u;
    }
    bx[(c << 3) + wid] = running + v - orig;            // exclusive, expert-local
    running += __shfl(v, 63, 64);
  }
  if (lane == 0) tot[wid] = running;
  __syncthreads();
  if (threadIdx.x == 0) {
    int off = 0, boff = 0;
    #pragma unroll
    for (int e = 0; e < 8; ++e) {
      ctrl[e] = tot[e];
      ctrl[8 + e] = off; eoff[e] = off; off += tot[e];
      ctrl[16 + e] = boff; boff += (tot[e] + 255) >> 8;  // 256-row M-groups
    }
    ctrl[24] = boff;
  }
  __syncthreads();
  for (int i = threadIdx.x; i < 2048; i += 512) base[i] = bx[i] + eoff[i & 7];
}

// ---------------- scatter (t,k) -> dense slots + inverse map ----------------
__global__ __launch_bounds__(256) void scatter_kernel(
    const int* __restrict__ tok_e, const int* __restrict__ tok_r, const float* __restrict__ tok_w,
    const int* __restrict__ base, int* __restrict__ slot_token, float* __restrict__ slot_w,
    int* __restrict__ tok_slot)
{
  int i = (blockIdx.x << 8) + threadIdx.x;
  int e = tok_e[i];
  int slot = base[((i >> 8) << 3) + e] + tok_r[i];
  slot_token[slot] = i >> 1;
  slot_w[slot] = tok_w[i];
  tok_slot[i] = slot;
}

// ---------------- expert_w fp32 [e][k][n] -> bf16 transposed Wt[e][n][k] ----------------
__global__ __launch_bounds__(256) void wconv_kernel(const float* __restrict__ w,
                                                    unsigned short* __restrict__ wt)
{
  __shared__ float tile[32][33];
  const float* we = w + ((size_t)blockIdx.z << 20);
  unsigned short* wte = wt + ((size_t)blockIdx.z << 20);
  int k0 = blockIdx.x << 5, n0 = blockIdx.y << 5;
  for (int i = threadIdx.x; i < 1024; i += 256) {
    int k = i >> 5, n = i & 31;
    tile[k][n] = we[(size_t)(k0 + k) * 1024 + n0 + n];
  }
  __syncthreads();
  for (int i = threadIdx.x; i < 1024; i += 256) {
    int n = i >> 5, k = i & 31;
    wte[(size_t)(n0 + n) * 1024 + k0 + k] = f2bf(tile[k][n]);
  }
}

// ---------------- grouped GEMM: 256x256, 8 waves (2Mx4N, 128x64/wave), m201 8-phase ----
// K-tiles of 64, split into K-half regions of 32. LDS [buf][khalf][256 rows][32k], 64B rows,
// slot swizzle s^((row>>1)&3) (uniform 2-way = free). Per tile t (buf cur), 4 phases:
//  ph1: rd aF(kh0)+bFa(kh0,nh0); stage Bk1(t+1)->nxt; BAR;lgkm0; 16 MFMA (nh0)
//  ph2: rd bFb(kh0,nh1);         stage Ak0(t+2)->cur; BAR;lgkm0; 16 MFMA (nh1)
//  ph3: rd aF(kh1)+bFa(kh1,nh0); stage Bk0(t+2)->cur; BAR;lgkm0; 16 MFMA (nh0)
//  ph4: rd bFb(kh1,nh1);         stage Ak1(t+2)->cur; vmcnt(6); BAR;lgkm0; 16 MFMA (nh1)
// vmcnt(6) leaves exactly 3 half-tiles (t+2) in flight and publishes all of t+1.
// Each staged region's prior-tile reads complete before any wave can issue the stage
// (reads -> lgkm(0) -> closing barrier -> next-phase stage issue).
__global__ __launch_bounds__(512, 2) void moe_gemm(
    const unsigned short* __restrict__ xb, const unsigned short* __restrict__ wt,
    const float* __restrict__ bias, const int* __restrict__ ctrl,
    const int* __restrict__ slot_token, const float* __restrict__ slot_w,
    float* __restrict__ ybuf, float* __restrict__ out, int total_slots, int use_ybuf)
{
  __shared__ unsigned short Alds[2 * 2 * 256 * 32];   // 64 KB: [buf][khalf][row][32k]
  __shared__ unsigned short Blds[2 * 2 * 256 * 32];   // 64 KB
  __shared__ int   tokid[256];
  __shared__ float wrow[256];

  // dispatch map: 4 N-blocks of an M-group share one XCD (d&7)
  int d = blockIdx.x;
  int xcd = d & 7, nb = (d >> 3) & 3, gbase = d >> 5;
  int by = (gbase << 3) | xcd;                    // M-group id
  if (by >= ctrl[24]) return;
  int e = 0;
  #pragma unroll
  for (int i = 1; i < 8; ++i) if (by >= ctrl[16 + i]) e = i;
  int mblk = by - ctrl[16 + e];
  int cnt  = ctrl[e];
  int slot0 = ctrl[8 + e] + (mblk << 8);
  int rows_valid = cnt - (mblk << 8); if (rows_valid > 256) rows_valid = 256;

  int tid = threadIdx.x;
  if (tid < 256) {
    int s = slot0 + tid; if (s > total_slots - 1) s = total_slots - 1;
    tokid[tid] = slot_token[s];
    wrow[tid]  = slot_w[s];
  }
  __syncthreads();

  int lane = tid & 63, w = tid >> 6;
  int wm = w >> 2, wn = w & 3;                    // wave grid 2M x 4N; 128x64 out per wave
  int l15 = lane & 15, hk = lane >> 4;            // hk = 16B k-block within 32-k region
  int bn0 = nb << 8;
  const unsigned short* wte = wt + ((size_t)e << 20);

  // staging: per half-tile (128 rows x 32 k = 16 KB) each thread does 2 x 16B loads.
  // flat j = tid (+512): row = j>>2, slot = j&3; src k-block = slot ^ ((row>>1)&3).
  int rr = tid >> 2;                              // 0..127
  int kswz = (tid & 3) ^ ((tid >> 3) & 3);
  const unsigned short* gA0 = xb + ((size_t)tokid[rr] << 10) + (kswz << 3);
  const unsigned short* gA1 = xb + ((size_t)tokid[128 + rr] << 10) + (kswz << 3);
  const unsigned short* gB0 = wte + ((size_t)(bn0 + rr) << 10) + (kswz << 3);
  const unsigned short* gB1 = wte + ((size_t)(bn0 + 128 + rr) << 10) + (kswz << 3);

  f32x4_t acc[8][4] = {};
  short8_t aF[8], bFa[2], bFb[2];

// stage one half-tile (KH of tile T) into buffer BUF (0 or 16384 shorts)
#define STG_A(BUF, KH, T)                                                               \
  GLOAD_LDS16(gA0 + ((T) << 6) + ((KH) << 5), &Alds[(BUF) + ((KH) << 13) + (w << 9)]);  \
  GLOAD_LDS16(gA1 + ((T) << 6) + ((KH) << 5), &Alds[(BUF) + ((KH) << 13) + 4096 + (w << 9)]);
#define STG_B(BUF, KH, T)                                                               \
  GLOAD_LDS16(gB0 + ((T) << 6) + ((KH) << 5), &Blds[(BUF) + ((KH) << 13) + (w << 9)]);  \
  GLOAD_LDS16(gB1 + ((T) << 6) + ((KH) << 5), &Blds[(BUF) + ((KH) << 13) + 4096 + (w << 9)]);

#define RD_AF(BUF, KH)                                                                  \
  _Pragma("unroll") for (int mf = 0; mf < 8; ++mf) {                                    \
    int ar = (wm << 7) + (mf << 4) + l15;                                               \
    aF[mf] = *(const short8_t*)&Alds[(BUF) + ((KH) << 13) + (ar << 5) + ((hk ^ ((ar >> 1) & 3)) << 3)]; }
#define RD_BF(DST, BUF, KH, NH)                                                         \
  _Pragma("unroll") for (int i = 0; i < 2; ++i) {                                       \
    int br = (wn << 6) + ((((NH) << 1) + i) << 4) + l15;                                \
    DST[i] = *(const short8_t*)&Blds[(BUF) + ((KH) << 13) + (br << 5) + ((hk ^ ((br >> 1) & 3)) << 3)]; }

#define MM(NH, BF)                                                                      \
  __builtin_amdgcn_s_setprio(1);                                                        \
  _Pragma("unroll") for (int mf = 0; mf < 8; ++mf)                                      \
  _Pragma("unroll") for (int i = 0; i < 2; ++i)                                         \
    acc[mf][((NH) << 1) + i] = __builtin_amdgcn_mfma_f32_16x16x32_bf16(                 \
        aF[mf], BF[i], acc[mf][((NH) << 1) + i], 0, 0, 0);                              \
  __builtin_amdgcn_s_setprio(0);

#define PH_SYNC                                                                         \
  __builtin_amdgcn_s_barrier();                                                         \
  asm volatile("s_waitcnt lgkmcnt(0)" ::: "memory");                                    \
  __builtin_amdgcn_sched_barrier(0);
#define BARR __builtin_amdgcn_s_barrier();

  // prologue: tile0 (4 half-tiles); vmcnt(4); tile1 (3 half-tiles); vmcnt(6); barrier
  STG_A(0, 0, 0) STG_B(0, 0, 0) STG_A(0, 1, 0) STG_B(0, 1, 0)
  asm volatile("s_waitcnt vmcnt(4)" ::: "memory");
  STG_A(16384, 0, 1) STG_B(16384, 0, 1) STG_A(16384, 1, 1)
  asm volatile("s_waitcnt vmcnt(6)" ::: "memory");
  BARR

  int cur = 0;
  for (int t = 0; t < 16; ++t) {
    int nxt = cur ^ 16384;
    // ph1
    RD_AF(cur, 0) RD_BF(bFa, cur, 0, 0)
    if (t < 15) { STG_B(nxt, 1, t + 1) }
    PH_SYNC
    MM(0, bFa)
    BARR
    // ph2
    RD_BF(bFb, cur, 0, 1)
    if (t < 14) { STG_A(cur, 0, t + 2) }
    PH_SYNC
    MM(1, bFb)
    BARR
    // ph3
    RD_AF(cur, 1) RD_BF(bFa, cur, 1, 0)
    if (t < 14) { STG_B(cur, 0, t + 2) }
    PH_SYNC
    MM(0, bFa)
    BARR
    // ph4
    RD_BF(bFb, cur, 1, 1)
    if (t < 14) { STG_A(cur, 1, t + 2) }
    if (t < 14) { asm volatile("s_waitcnt vmcnt(6)" ::: "memory"); }
    else if (t == 14) { asm volatile("s_waitcnt vmcnt(0)" ::: "memory"); }
    PH_SYNC
    MM(1, bFb)
    BARR
    cur = nxt;
  }
#undef STG_A
#undef STG_B
#undef RD_AF
#undef RD_BF
#undef MM
#undef PH_SYNC
#undef BARR

  const float* be = bias + (e << 10);
  float bv[4];
  #pragma unroll
  for (int nf = 0; nf < 4; ++nf) bv[nf] = be[bn0 + (wn << 6) + (nf << 4) + l15];
  #pragma unroll
  for (int mf = 0; mf < 8; ++mf) {
    int rbase = (wm << 7) + (mf << 4) + (hk << 2);
    #pragma unroll
    for (int r = 0; r < 4; ++r) {
      int row = rbase + r;
      if (row < rows_valid) {
        float wv = wrow[row];
        if (use_ybuf) {
          size_t obase = ((size_t)(slot0 + row) << 10);
          #pragma unroll
          for (int nf = 0; nf < 4; ++nf) {        // 4 back-to-back 64B stores per 256B line
            int dout = bn0 + (wn << 6) + (nf << 4) + l15;
            ybuf[obase + dout] = wv * (acc[mf][nf][r] + bv[nf]);
          }
        } else {
          size_t obase = ((size_t)tokid[row] << 10);
          #pragma unroll
          for (int nf = 0; nf < 4; ++nf) {
            int dout = bn0 + (wn << 6) + (nf << 4) + l15;
            atomicAdd(&out[obase + dout], wv * (acc[mf][nf][r] + bv[nf]));
          }
        }
      }
    }
  }
}

// ---------------- combine: out[t] = ybuf[slot0(t)] + ybuf[slot1(t)] ----------------
__global__ __launch_bounds__(256) void combine_kernel(
    const float* __restrict__ ybuf, const int* __restrict__ tok_slot, float* __restrict__ out)
{
  int t = blockIdx.x;
  int s0 = tok_slot[t << 1], s1 = tok_slot[(t << 1) + 1];
  const float4* y0 = (const float4*)(ybuf + ((size_t)s0 << 10));
  const float4* y1 = (const float4*)(ybuf + ((size_t)s1 << 10));
  float4 a = y0[threadIdx.x], b = y1[threadIdx.x];
  float4 r; r.x = a.x + b.x; r.y = a.y + b.y; r.z = a.z + b.z; r.w = a.w + b.w;
  ((float4*)(out + ((size_t)t << 10)))[threadIdx.x] = r;
}

extern "C" void kernel_launch(void* const* d_in, const int* in_sizes, int n_in,
                              void* d_out, int out_size, void* d_ws, size_t ws_size,
                              hipStream_t stream) {
  (void)n_in;
  const float* x  = (const float*)d_in[0];
  const float* gw = (const float*)d_in[1];
  const float* ew = (const float*)d_in[2];
  const float* eb = (const float*)d_in[3];
  int T  = in_sizes[0] >> 10;   // 32768
  int T2 = T << 1;              // 65536 slots

  // workspace layout
  char* wsb = (char*)d_ws;
  unsigned short* xb = (unsigned short*)wsb;
  size_t off = (size_t)T * 1024 * 2;                    // x bf16: 64 MB
  unsigned short* wt = (unsigned short*)(wsb + off);
  off += (size_t)8 * 1024 * 1024 * 2;                   // Wt bf16: 16 MB
  int* ctrl = (int*)(wsb + off); off += 256;
  int* tok_e = (int*)(wsb + off); off += (size_t)T2 * 4;
  int* tok_r = (int*)(wsb + off); off += (size_t)T2 * 4;
  float* tok_w = (float*)(wsb + off); off += (size_t)T2 * 4;
  int* slot_token = (int*)(wsb + off); off += (size_t)T2 * 4;
  float* slot_w = (float*)(wsb + off); off += (size_t)T2 * 4;
  int* tok_slot = (int*)(wsb + off); off += (size_t)T2 * 4;
  int* chunkhist = (int*)(wsb + off); off += 2048 * 4;
  int* base = (int*)(wsb + off); off += 2048 * 4;
  float* ybuf = (float*)(wsb + off);
  size_t need = off + (size_t)T2 * 1024 * 4;            // +268 MB
  int use_ybuf = (ws_size >= need) ? 1 : 0;

  float* out = (float*)d_out;

  if (!use_ybuf)
    hipMemsetAsync(d_out, 0, (size_t)out_size * sizeof(float), stream);
  gate_kernel<<<T / 16, 256, 0, stream>>>(x, gw, xb, tok_e, tok_w);
  wconv_kernel<<<dim3(32, 32, 8), 256, 0, stream>>>(ew, wt);
  hist_kernel<<<T2 / 256, 256, 0, stream>>>(tok_e, tok_r, chunkhist);
  scan_kernel<<<1, 512, 0, stream>>>(chunkhist, base, ctrl);
  scatter_kernel<<<T2 / 256, 256, 0, stream>>>(tok_e, tok_r, tok_w, base,
                                               slot_token, slot_w, tok_slot);
  // up to 264 M-groups (256 rows, padded to x8) x 4 N-blocks
  moe_gemm<<<1056, 512, 0, stream>>>(xb, wt, eb, ctrl, slot_token, slot_w,
                                     ybuf, out, T2, use_ybuf);
  if (use_ybuf)
    combine_kernel<<<T, 256, 0, stream>>>(ybuf, tok_slot, out);
}

// Round 10
// 307.926 us; speedup vs baseline: 1.3753x; 1.3753x over previous
//
#include <hip/hip_runtime.h>
#include <hip/hip_bf16.h>

// MoE top-2, T=32768 tokens, D=1024, E=8.
// Pipeline: gate(4 tok/wave) -> hist -> scan -> scatter(packed k-slot) -> wconv
//           -> grouped GEMM (128x256, 4 waves of 64x128, 3-buf ring, vmcnt(6), 2 blk/CU)
//           -> combine (bf16 partials -> fp32 out).

typedef __attribute__((ext_vector_type(8))) short short8_t;
typedef __attribute__((ext_vector_type(4))) float f32x4_t;
typedef __attribute__((ext_vector_type(4))) unsigned short us4_t;

#define GLOAD_LDS16(g, l)                                                                     \
  __builtin_amdgcn_global_load_lds((const __attribute__((address_space(1))) unsigned int*)(g), \
                                   (__attribute__((address_space(3))) unsigned int*)(l), 16, 0, 0)

__device__ __forceinline__ unsigned short f2bf(float f) {
  union { __hip_bfloat16 h; unsigned short u; } c;
  c.h = __float2bfloat16(f);
  return c.u;
}
__device__ __forceinline__ float bf2f(unsigned short u) {
  union { unsigned int i; float f; } c;
  c.i = ((unsigned int)u) << 16;
  return c.f;
}

// ---------------- gate: 4 tokens/wave; fp32 logits, top-2 softmax; x -> bf16 ----------------
__global__ __launch_bounds__(256) void gate_kernel(
    const float* __restrict__ x, const float* __restrict__ gw,
    unsigned short* __restrict__ xb,
    int* __restrict__ tok_e, float* __restrict__ tok_w)
{
  int wid = threadIdx.x >> 6, lane = threadIdx.x & 63;
  int t0 = (blockIdx.x << 4) + (wid << 2);              // 4 tokens per wave
  const float4* g4 = (const float4*)gw;                 // gw is [1024][8] row-major
  float lg[4][8] = {};
  #pragma unroll
  for (int c = 0; c < 4; ++c) {
    int d4 = (c << 6) + lane;                           // float4 index within a row
    float4 ga[4], gb[4];
    #pragma unroll
    for (int j = 0; j < 4; ++j) {
      int d = (d4 << 2) + j;
      ga[j] = g4[d << 1];
      gb[j] = g4[(d << 1) + 1];
    }
    #pragma unroll
    for (int t = 0; t < 4; ++t) {                       // reuse gw regs across 4 tokens
      const float4* x4 = (const float4*)(x + ((size_t)(t0 + t) << 10));
      float4 v = x4[d4];
      unsigned long long pk = (unsigned long long)f2bf(v.x)
                            | ((unsigned long long)f2bf(v.y) << 16)
                            | ((unsigned long long)f2bf(v.z) << 32)
                            | ((unsigned long long)f2bf(v.w) << 48);
      ((unsigned long long*)(xb + ((size_t)(t0 + t) << 10)))[d4] = pk;
      float xs[4] = {v.x, v.y, v.z, v.w};
      #pragma unroll
      for (int j = 0; j < 4; ++j) {
        lg[t][0] += xs[j]*ga[j].x; lg[t][1] += xs[j]*ga[j].y;
        lg[t][2] += xs[j]*ga[j].z; lg[t][3] += xs[j]*ga[j].w;
        lg[t][4] += xs[j]*gb[j].x; lg[t][5] += xs[j]*gb[j].y;
        lg[t][6] += xs[j]*gb[j].z; lg[t][7] += xs[j]*gb[j].w;
      }
    }
  }
  #pragma unroll
  for (int t = 0; t < 4; ++t)
    #pragma unroll
    for (int e = 0; e < 8; ++e) {
      float v = lg[t][e];
      #pragma unroll
      for (int s = 32; s > 0; s >>= 1) v += __shfl_xor(v, s, 64);
      lg[t][e] = v;
    }
  if (lane < 4) {                                       // lane t finalizes token t0+t
    int t = t0 + lane;
    float m0 = lg[lane][0], m1 = -3.4e38f; int e0 = 0, e1 = 0;
    #pragma unroll
    for (int e = 1; e < 8; ++e) {                       // strict '>' matches jax top_k ties
      float v = lg[lane][e];
      if (v > m0) { m1 = m0; e1 = e0; m0 = v; e0 = e; }
      else if (v > m1) { m1 = v; e1 = e; }
    }
    float p1 = 1.0f / (1.0f + expf(m0 - m1));
    float p0 = 1.0f - p1;
    int i0 = t << 1;
    tok_e[i0]   = e0; tok_w[i0]   = p0;
    tok_e[i0+1] = e1; tok_w[i0+1] = p1;
  }
}

// ---------------- hist: per-256-entry chunk, LDS histogram + local rank ----------------
__global__ __launch_bounds__(256) void hist_kernel(
    const int* __restrict__ tok_e, int* __restrict__ tok_r, int* __restrict__ chunkhist)
{
  __shared__ int lh[8];
  if (threadIdx.x < 8) lh[threadIdx.x] = 0;
  __syncthreads();
  int i = (blockIdx.x << 8) + threadIdx.x;
  int e = tok_e[i];
  tok_r[i] = atomicAdd(&lh[e], 1);
  __syncthreads();
  if (threadIdx.x < 8) chunkhist[(blockIdx.x << 3) + threadIdx.x] = lh[threadIdx.x];
}

// ---------------- scan: 8 waves, wave e scans expert e across 256 chunks ----------------
__global__ __launch_bounds__(512) void scan_kernel(
    const int* __restrict__ chunkhist, int* __restrict__ base, int* __restrict__ ctrl)
{
  __shared__ int h[2048];
  __shared__ int bx[2048];
  __shared__ int tot[8], eoff[8];
  for (int i = threadIdx.x; i < 2048; i += 512) h[i] = chunkhist[i];
  __syncthreads();
  int wid = threadIdx.x >> 6, lane = threadIdx.x & 63;
  int running = 0;
  #pragma unroll
  for (int b = 0; b < 4; ++b) {
    int c = (b << 6) + lane;
    int orig = h[(c << 3) + wid];
    int v = orig;
    #pragma unroll
    for (int s = 1; s < 64; s <<= 1) {
      int u = __shfl_up(v, s, 64);
      if (lane >= s) v += u;
    }
    bx[(c << 3) + wid] = running + v - orig;            // exclusive, expert-local
    running += __shfl(v, 63, 64);
  }
  if (lane == 0) tot[wid] = running;
  __syncthreads();
  if (threadIdx.x == 0) {
    int off = 0, boff = 0;
    #pragma unroll
    for (int e = 0; e < 8; ++e) {
      ctrl[e] = tot[e];
      ctrl[8 + e] = off; eoff[e] = off; off += tot[e];
      ctrl[16 + e] = boff; boff += (tot[e] + 127) >> 7;  // 128-row M-groups
    }
    ctrl[24] = boff;
  }
  __syncthreads();
  for (int i = threadIdx.x; i < 2048; i += 512) base[i] = bx[i] + eoff[i & 7];
}

// ---------------- scatter (t,k) -> dense slots; token + k-slot packed ----------------
__global__ __launch_bounds__(256) void scatter_kernel(
    const int* __restrict__ tok_e, const int* __restrict__ tok_r, const float* __restrict__ tok_w,
    const int* __restrict__ base, int* __restrict__ slot_token, float* __restrict__ slot_w)
{
  int i = (blockIdx.x << 8) + threadIdx.x;
  int e = tok_e[i];
  int slot = base[((i >> 8) << 3) + e] + tok_r[i];
  slot_token[slot] = (i >> 1) | ((i & 1) << 16);       // token | kslot<<16
  slot_w[slot] = tok_w[i];
}

// ---------------- expert_w fp32 [e][k][n] -> bf16 transposed Wt[e][n][k] ----------------
__global__ __launch_bounds__(256) void wconv_kernel(const float* __restrict__ w,
                                                    unsigned short* __restrict__ wt)
{
  __shared__ float tile[32][33];
  const float* we = w + ((size_t)blockIdx.z << 20);
  unsigned short* wte = wt + ((size_t)blockIdx.z << 20);
  int k0 = blockIdx.x << 5, n0 = blockIdx.y << 5;
  for (int i = threadIdx.x; i < 1024; i += 256) {
    int k = i >> 5, n = i & 31;
    tile[k][n] = we[(size_t)(k0 + k) * 1024 + n0 + n];
  }
  __syncthreads();
  for (int i = threadIdx.x; i < 1024; i += 256) {
    int n = i >> 5, k = i & 31;
    wte[(size_t)(n0 + n) * 1024 + k0 + k] = f2bf(tile[k][n]);
  }
}

// ---------------- grouped GEMM: 128x256 tile, 4 waves of 64x128, BK=32, 3-buf ring ----
// Same sync structure as the best-measured r8 kernel (1 barrier/tile, vmcnt(6), 2-deep
// ring); wave tile widened to 64x128 -> 42.7 FLOP per LDS byte (was 32). 2 blocks/CU.
// LDS slot s of row r holds global 16B k-block s^((r>>1)&3) (both-sides swizzle, 0
// conflicts measured). Epilogue: bf16 partials to part[token][kslot][d] (exactly one
// writer per (t,k,d) -> no atomics, deterministic).
__global__ __launch_bounds__(256, 2) void moe_gemm(
    const unsigned short* __restrict__ xb, const unsigned short* __restrict__ wt,
    const float* __restrict__ bias, const int* __restrict__ ctrl,
    const int* __restrict__ slot_token, const float* __restrict__ slot_w,
    unsigned short* __restrict__ part, float* __restrict__ out, int total_slots, int use_part)
{
  __shared__ unsigned short Alds[3 * 128 * 32];   // 24 KB: [buf][row][32k]
  __shared__ unsigned short Blds[3 * 256 * 32];   // 48 KB
  __shared__ int   tokid[128];
  __shared__ int   kslot[128];
  __shared__ float wrow[128];

  // dispatch map: 4 N-blocks of an M-group share one XCD (d&7)
  int d = blockIdx.x;
  int xcd = d & 7, nb = (d >> 3) & 3, gbase = d >> 5;
  int by = (gbase << 3) | xcd;                    // M-group id
  if (by >= ctrl[24]) return;
  int e = 0;
  #pragma unroll
  for (int i = 1; i < 8; ++i) if (by >= ctrl[16 + i]) e = i;
  int mblk = by - ctrl[16 + e];
  int cnt  = ctrl[e];
  int slot0 = ctrl[8 + e] + (mblk << 7);
  int rows_valid = cnt - (mblk << 7); if (rows_valid > 128) rows_valid = 128;

  int tid = threadIdx.x;
  if (tid < 128) {
    int s = slot0 + tid; if (s > total_slots - 1) s = total_slots - 1;
    int v = slot_token[s];
    tokid[tid] = v & 0xFFFF;
    kslot[tid] = v >> 16;
    wrow[tid]  = slot_w[s];
  }
  __syncthreads();

  int lane = tid & 63, w = tid >> 6;
  int wm = w >> 1, wn = w & 1;                    // wave grid 2x2; 64 rows x 128 cols/wave
  int l15 = lane & 15, hk = lane >> 4;
  int bn0 = nb << 8;                              // 256-wide N-block
  const unsigned short* wte = wt + ((size_t)e << 20);

  // staging: 16B chunk c -> row c>>2, LDS slot c&3; src k-block (c&3)^((row>>1)&3).
  // A: 512 chunks (2/thread), B: 1024 chunks (4/thread).
  int rr = tid >> 2;                              // 0..63
  int kswz = (tid & 3) ^ ((tid >> 3) & 3);
  const unsigned short* gA0 = xb + ((size_t)tokid[rr] << 10) + (kswz << 3);
  const unsigned short* gA1 = xb + ((size_t)tokid[64 + rr] << 10) + (kswz << 3);
  const unsigned short* gB0 = wte + ((size_t)(bn0 + rr) << 10) + (kswz << 3);
  const unsigned short* gB1 = wte + ((size_t)(bn0 + 64 + rr) << 10) + (kswz << 3);
  const unsigned short* gB2 = wte + ((size_t)(bn0 + 128 + rr) << 10) + (kswz << 3);
  const unsigned short* gB3 = wte + ((size_t)(bn0 + 192 + rr) << 10) + (kswz << 3);
  int wbase = w << 9;                             // wave-uniform dest (shorts)

  f32x4_t acc[4][8] = {};

#define STAGE(NB, KO)                                                         \
  GLOAD_LDS16(gA0 + (KO), &Alds[(NB) * 4096 + wbase]);                        \
  GLOAD_LDS16(gA1 + (KO), &Alds[(NB) * 4096 + 2048 + wbase]);                 \
  GLOAD_LDS16(gB0 + (KO), &Blds[(NB) * 8192 + wbase]);                        \
  GLOAD_LDS16(gB1 + (KO), &Blds[(NB) * 8192 + 2048 + wbase]);                 \
  GLOAD_LDS16(gB2 + (KO), &Blds[(NB) * 8192 + 4096 + wbase]);                 \
  GLOAD_LDS16(gB3 + (KO), &Blds[(NB) * 8192 + 6144 + wbase]);

#define COMPUTE(BUF)                                                          \
  { short8_t aF[4], bF[8];                                                    \
    _Pragma("unroll") for (int m = 0; m < 4; ++m) {                           \
      int ar = (wm << 6) + (m << 4) + l15;                                    \
      aF[m] = *(const short8_t*)&Alds[(BUF) * 4096 + (ar << 5) + ((hk ^ ((ar >> 1) & 3)) << 3)]; } \
    _Pragma("unroll") for (int n = 0; n < 8; ++n) {                           \
      int br = (wn << 7) + (n << 4) + l15;                                    \
      bF[n] = *(const short8_t*)&Blds[(BUF) * 8192 + (br << 5) + ((hk ^ ((br >> 1) & 3)) << 3)]; } \
    __builtin_amdgcn_s_setprio(1);                                            \
    _Pragma("unroll") for (int m = 0; m < 4; ++m)                             \
    _Pragma("unroll") for (int n = 0; n < 8; ++n)                             \
      acc[m][n] = __builtin_amdgcn_mfma_f32_16x16x32_bf16(aF[m], bF[n], acc[m][n], 0, 0, 0); \
    __builtin_amdgcn_s_setprio(0); }

#define VM6 asm volatile("s_waitcnt vmcnt(6)" ::: "memory");
#define BARR __builtin_amdgcn_s_barrier();

  // prologue: stage tiles 0 -> buf0, 1 -> buf1; wait tile 0; barrier
  STAGE(0, 0)
  STAGE(1, 32)
  VM6
  BARR
  // main loop: tiles 0..29 (each stages t+2; vmcnt(6) retires t+1)
  for (int i = 0; i < 10; ++i) {
    int t = i * 3;
    STAGE(2, (t + 2) << 5)
    COMPUTE(0)
    VM6
    BARR
    STAGE(0, (t + 3) << 5)
    COMPUTE(1)
    VM6
    BARR
    STAGE(1, (t + 4) << 5)
    COMPUTE(2)
    VM6
    BARR
  }
  // tail: tile 30 (buf0; drain tile 31), tile 31 (buf1)
  COMPUTE(0)
  asm volatile("s_waitcnt vmcnt(0)" ::: "memory");
  BARR
  COMPUTE(1)
#undef STAGE
#undef COMPUTE
#undef VM6
#undef BARR

  const float* be = bias + (e << 10);
  float bv[8];
  #pragma unroll
  for (int nf = 0; nf < 8; ++nf) bv[nf] = be[bn0 + (wn << 7) + (nf << 4) + l15];
  #pragma unroll
  for (int mf = 0; mf < 4; ++mf) {
    int rbase = (wm << 6) + (mf << 4) + (hk << 2);
    #pragma unroll
    for (int r = 0; r < 4; ++r) {
      int row = rbase + r;
      if (row < rows_valid) {
        float wv = wrow[row];
        if (use_part) {
          size_t obase = ((size_t)((tokid[row] << 1) | kslot[row]) << 10);
          #pragma unroll
          for (int nf = 0; nf < 8; ++nf) {
            int dout = bn0 + (wn << 7) + (nf << 4) + l15;
            part[obase + dout] = f2bf(wv * (acc[mf][nf][r] + bv[nf]));
          }
        } else {
          size_t obase = ((size_t)tokid[row] << 10);
          #pragma unroll
          for (int nf = 0; nf < 8; ++nf) {
            int dout = bn0 + (wn << 7) + (nf << 4) + l15;
            atomicAdd(&out[obase + dout], wv * (acc[mf][nf][r] + bv[nf]));
          }
        }
      }
    }
  }
}

// ---------------- combine: out[t][d] = part[t][0][d] + part[t][1][d] ----------------
__global__ __launch_bounds__(256) void combine_kernel(
    const unsigned short* __restrict__ part, float* __restrict__ out)
{
  int t = blockIdx.x, i = threadIdx.x;                 // 4 d's per thread
  const us4_t* p0 = (const us4_t*)(part + ((size_t)(t << 1) << 10));
  const us4_t* p1 = (const us4_t*)(part + ((size_t)((t << 1) | 1) << 10));
  us4_t a = p0[i], b = p1[i];
  float4 r;
  r.x = bf2f(a.x) + bf2f(b.x);
  r.y = bf2f(a.y) + bf2f(b.y);
  r.z = bf2f(a.z) + bf2f(b.z);
  r.w = bf2f(a.w) + bf2f(b.w);
  ((float4*)(out + ((size_t)t << 10)))[i] = r;
}

extern "C" void kernel_launch(void* const* d_in, const int* in_sizes, int n_in,
                              void* d_out, int out_size, void* d_ws, size_t ws_size,
                              hipStream_t stream) {
  (void)n_in;
  const float* x  = (const float*)d_in[0];
  const float* gw = (const float*)d_in[1];
  const float* ew = (const float*)d_in[2];
  const float* eb = (const float*)d_in[3];
  int T  = in_sizes[0] >> 10;   // 32768
  int T2 = T << 1;              // 65536 slots

  // workspace layout
  char* wsb = (char*)d_ws;
  unsigned short* xb = (unsigned short*)wsb;
  size_t off = (size_t)T * 1024 * 2;                    // x bf16: 64 MB
  unsigned short* wt = (unsigned short*)(wsb + off);
  off += (size_t)8 * 1024 * 1024 * 2;                   // Wt bf16: 16 MB
  int* ctrl = (int*)(wsb + off); off += 256;
  int* tok_e = (int*)(wsb + off); off += (size_t)T2 * 4;
  int* tok_r = (int*)(wsb + off); off += (size_t)T2 * 4;
  float* tok_w = (float*)(wsb + off); off += (size_t)T2 * 4;
  int* slot_token = (int*)(wsb + off); off += (size_t)T2 * 4;
  float* slot_w = (float*)(wsb + off); off += (size_t)T2 * 4;
  int* chunkhist = (int*)(wsb + off); off += 2048 * 4;
  int* base = (int*)(wsb + off); off += 2048 * 4;
  unsigned short* part = (unsigned short*)(wsb + off);
  size_t need = off + (size_t)T2 * 1024 * 2;            // +134 MB bf16 partials
  int use_part = (ws_size >= need) ? 1 : 0;

  float* out = (float*)d_out;

  if (!use_part)
    hipMemsetAsync(d_out, 0, (size_t)out_size * sizeof(float), stream);
  gate_kernel<<<T / 16, 256, 0, stream>>>(x, gw, xb, tok_e, tok_w);
  wconv_kernel<<<dim3(32, 32, 8), 256, 0, stream>>>(ew, wt);
  hist_kernel<<<T2 / 256, 256, 0, stream>>>(tok_e, tok_r, chunkhist);
  scan_kernel<<<1, 512, 0, stream>>>(chunkhist, base, ctrl);
  scatter_kernel<<<T2 / 256, 256, 0, stream>>>(tok_e, tok_r, tok_w, base,
                                               slot_token, slot_w);
  // up to 520 M-groups (128 rows) x 4 N-blocks (256 wide)
  moe_gemm<<<2080, 256, 0, stream>>>(xb, wt, eb, ctrl, slot_token, slot_w,
                                     part, out, T2, use_part);
  if (use_part)
    combine_kernel<<<T, 256, 0, stream>>>(part, out);
}